// Round 8
// baseline (420.905 us; speedup 1.0000x reference)
//
#include <hip/hip_runtime.h>
#include <hip/hip_bf16.h>

// FactorizedDenseAttention, MI355X/gfx950.  ALL I/O FP32.
// S[i,j] = sum_m C[i,m]*B[j,m], C = 32*(a[2m]+a[2m+1]) (rank 32)
//   a = q@Wa^T+ba (64ch), B = q@Wb^T+bb (32ch); P = softmax(S); O = P@v.
// S via hi/lo bf16 Dekker split -> 4 MFMAs (16x16x32); stats and P passes
// run bitwise-identical MFMA sequences so exp(S-m)<=1, =1 at the max.
// d_out = [O: H*L*64 f32][P: H*L*L f32].
// R8 (LDS-pipe + occupancy attack; R7 dbuf was neutral => not DMA-latency):
//   k_stats split out, j/4 (2048 blocks, lean = high occupancy for exp);
//   k_pv j/2 (1024 blocks = 16 waves/CU) + O partials + k_ored reduce;
//   Psf dropped (P stored NT scalar from acc); Vt read from global/L2.

#define HN 16
#define LN 2048
#define KR 32

typedef __attribute__((ext_vector_type(8))) short bf16x8;
typedef __attribute__((ext_vector_type(4))) float f32x4;

__device__ __forceinline__ float b2f(unsigned short u) {
    return __uint_as_float(((unsigned int)u) << 16);
}
__device__ __forceinline__ unsigned short f2b(float f) {
    __hip_bfloat16 h = __float2bfloat16(f);   // RNE
    return *reinterpret_cast<unsigned short*>(&h);
}
__device__ __forceinline__ void glds16(const void* g, void* l) {
    // src: per-lane global addr; dst: wave-uniform LDS base (HW adds lane*16)
    __builtin_amdgcn_global_load_lds(
        (const __attribute__((address_space(1))) unsigned int*)g,
        (__attribute__((address_space(3))) unsigned int*)l, 16, 0, 0);
}

// B-tile per (h, jc): 8KB = 4096 shorts:
//   [0,    2048): Bhi  [kg=0..3][c=0..63] granules of 8 bf16 (k=kg*8..+8)
//   [2048, 4096): Blo  same layout
#define TILE_B 4096

// ---------------------------------------------------------------------------
// K1a: thread = (row, kg): 8 m's. Weights in LDS. Chi/Clo row-major,
// Bhi/Blo in 8KB tile layout.
// ---------------------------------------------------------------------------
__global__ __launch_bounds__(256) void k_cb(
    const float* __restrict__ q,
    const float* __restrict__ Wa, const float* __restrict__ ba,
    const float* __restrict__ Wb, const float* __restrict__ bb,
    unsigned short* __restrict__ Chi, unsigned short* __restrict__ Clo,
    unsigned short* __restrict__ TileB)
{
    __shared__ float sWa[64 * 64];
    __shared__ float sWb[32 * 64];
    __shared__ float sba[64];
    __shared__ float sbb[32];
    const int tid = threadIdx.x;
    for (int i = tid; i < 64 * 64; i += 256) sWa[i] = Wa[i];
    for (int i = tid; i < 32 * 64; i += 256) sWb[i] = Wb[i];
    if (tid < 64) sba[tid] = ba[tid];
    if (tid < 32) sbb[tid] = bb[tid];
    __syncthreads();

    const int t = blockIdx.x * 256 + tid;
    const int row = t >> 2, kg = t & 3, mh = kg * 8;   // m in [mh, mh+8)
    const int h = row >> 11, i = row & 2047;
    const int jc = i >> 6, c = i & 63;

    float qf[64];
    const float4* q4p = reinterpret_cast<const float4*>(q + (size_t)row * 64);
    #pragma unroll
    for (int k4 = 0; k4 < 16; ++k4) {
        float4 u = q4p[k4];
        qf[4*k4+0] = u.x; qf[4*k4+1] = u.y; qf[4*k4+2] = u.z; qf[4*k4+3] = u.w;
    }
    unsigned short chb[8], clb[8], bhb[8], blb[8];
    #pragma unroll
    for (int mi = 0; mi < 8; ++mi) {
        const int m = mh + mi;
        float a0 = sba[2*m], a1 = sba[2*m+1], bv = sbb[m];
        const float4* wa0 = reinterpret_cast<const float4*>(&sWa[(2*m) * 64]);
        const float4* wa1 = reinterpret_cast<const float4*>(&sWa[(2*m+1) * 64]);
        const float4* wb0 = reinterpret_cast<const float4*>(&sWb[m * 64]);
        #pragma unroll
        for (int k4 = 0; k4 < 16; ++k4) {
            float4 w0 = wa0[k4], w1 = wa1[k4], w2 = wb0[k4];
            float x0 = qf[4*k4], x1 = qf[4*k4+1], x2 = qf[4*k4+2], x3 = qf[4*k4+3];
            a0 = fmaf(x0, w0.x, a0); a0 = fmaf(x1, w0.y, a0);
            a0 = fmaf(x2, w0.z, a0); a0 = fmaf(x3, w0.w, a0);
            a1 = fmaf(x0, w1.x, a1); a1 = fmaf(x1, w1.y, a1);
            a1 = fmaf(x2, w1.z, a1); a1 = fmaf(x3, w1.w, a1);
            bv = fmaf(x0, w2.x, bv); bv = fmaf(x1, w2.y, bv);
            bv = fmaf(x2, w2.z, bv); bv = fmaf(x3, w2.w, bv);
        }
        float cc = 32.f * (a0 + a1);                  // fold repeat factor
        unsigned short ch = f2b(cc);
        chb[mi] = ch; clb[mi] = f2b(cc - b2f(ch));
        unsigned short bh = f2b(bv);
        bhb[mi] = bh; blb[mi] = f2b(bv - b2f(bh));
    }
    *reinterpret_cast<uint4*>(Chi + (size_t)row * KR + mh) = *reinterpret_cast<uint4*>(chb);
    *reinterpret_cast<uint4*>(Clo + (size_t)row * KR + mh) = *reinterpret_cast<uint4*>(clb);
    unsigned short* tb = TileB + (size_t)(h * 32 + jc) * TILE_B + (kg * 64 + c) * 8;
    *reinterpret_cast<uint4*>(tb)        = *reinterpret_cast<uint4*>(bhb);
    *reinterpret_cast<uint4*>(tb + 2048) = *reinterpret_cast<uint4*>(blb);
}

// ---------------------------------------------------------------------------
// K1b: Vt[h][d][j] = bf16(v[h][j][d])  (transpose through LDS)
// ---------------------------------------------------------------------------
__global__ __launch_bounds__(256) void k_vt(
    const float* __restrict__ v, unsigned short* __restrict__ Vt)
{
    __shared__ unsigned short sv[64 * 66];
    const int tid = threadIdx.x;
    const int h = blockIdx.x >> 5, jt = blockIdx.x & 31;
    const float* src = v + (size_t)(h * LN + jt * 64) * 64;
    for (int i = tid; i < 4096; i += 256)
        sv[(i >> 6) * 66 + (i & 63)] = f2b(src[i]);
    __syncthreads();
    for (int i = tid; i < 4096; i += 256) {
        int d = i >> 6, j = i & 63;
        Vt[(size_t)(h * 64 + d) * LN + jt * 64 + j] = sv[j * 66 + d];
    }
}

// ---------------------------------------------------------------------------
// K2: partial row stats over 8 chunks (j/4 split). Lean kernel -> high
// occupancy for the exp-heavy pass. B tiles double-buffered via DMA.
// b: [2:0]=xcd, [7:3]=tile, [9:8]=j4, [10]=hbit; h=(b&7)*2+(b>>10).
// ---------------------------------------------------------------------------
__global__ __launch_bounds__(256) void k_stats(
    const unsigned short* __restrict__ Chi, const unsigned short* __restrict__ Clo,
    const unsigned short* __restrict__ TileB,
    float* __restrict__ rowM4, float* __restrict__ rowL4)
{
    __shared__ unsigned short sB[2][TILE_B];    // 2 x 8KB
    const int b = blockIdx.x;
    const int h = (b & 7) * 2 + (b >> 10);
    const int tile = (b >> 3) & 31;
    const int j4 = (b >> 8) & 3;
    const int tid = threadIdx.x, w = tid >> 6, lane = tid & 63;
    const int quad = lane >> 4, n16 = lane & 15;
    const int rbase = tile * 64 + w * 16;
    const int hL = h * LN;

    const bf16x8 ahi = *reinterpret_cast<const bf16x8*>(Chi + (size_t)(hL + rbase + n16) * KR + quad * 8);
    const bf16x8 alo = *reinterpret_cast<const bf16x8*>(Clo + (size_t)(hL + rbase + n16) * KR + quad * 8);

    const char* tBase = (const char*)(TileB + (size_t)(h * 32) * TILE_B);
    const int fragB = (quad * 64 + n16) * 8;
    const int srcOff = w * 2048 + lane * 16;
    const int jc0 = j4 * 8;

    f32x4 zero = {0.f, 0.f, 0.f, 0.f};
    float m0[4] = {-1e30f, -1e30f, -1e30f, -1e30f};
    float l0[4] = {0.f, 0.f, 0.f, 0.f};

    {   // prologue: chunk jc0 -> buf 0
        const char* g = tBase + (size_t)jc0 * 8192;
        char* d = (char*)sB[0];
        glds16(g + srcOff, d + w * 2048);
        glds16(g + srcOff + 1024, d + w * 2048 + 1024);
    }
    for (int ji = 0; ji < 8; ++ji) {
        __syncthreads();                         // drain DMA(cur) + prev compute
        const int cur = ji & 1;
        if (ji + 1 < 8) {
            const char* g = tBase + (size_t)(jc0 + ji + 1) * 8192;
            char* d = (char*)sB[cur ^ 1];
            glds16(g + srcOff, d + w * 2048);
            glds16(g + srcOff + 1024, d + w * 2048 + 1024);
        }
        const unsigned short* t = sB[cur];
        f32x4 s[4];
        #pragma unroll
        for (int ni = 0; ni < 4; ++ni) {
            bf16x8 bhi = *reinterpret_cast<const bf16x8*>(t + fragB + ni * 128);
            bf16x8 blo = *reinterpret_cast<const bf16x8*>(t + 2048 + fragB + ni * 128);
            f32x4 acc = zero;
            acc = __builtin_amdgcn_mfma_f32_16x16x32_bf16(ahi, bhi, acc, 0, 0, 0);
            acc = __builtin_amdgcn_mfma_f32_16x16x32_bf16(ahi, blo, acc, 0, 0, 0);
            acc = __builtin_amdgcn_mfma_f32_16x16x32_bf16(alo, bhi, acc, 0, 0, 0);
            acc = __builtin_amdgcn_mfma_f32_16x16x32_bf16(alo, blo, acc, 0, 0, 0);
            s[ni] = acc;
        }
        #pragma unroll
        for (int r = 0; r < 4; ++r) {
            float v0 = s[0][r], v1 = s[1][r], v2 = s[2][r], v3 = s[3][r];
            float mx = fmaxf(fmaxf(v0, v1), fmaxf(v2, v3));
            float mn = fmaxf(m0[r], mx);
            l0[r] = l0[r] * __expf(m0[r] - mn)
                  + __expf(v0 - mn) + __expf(v1 - mn)
                  + __expf(v2 - mn) + __expf(v3 - mn);
            m0[r] = mn;
        }
    }
    #pragma unroll
    for (int off = 1; off <= 8; off <<= 1) {
        #pragma unroll
        for (int r = 0; r < 4; ++r) {
            float m2 = __shfl_xor(m0[r], off, 64);
            float l2 = __shfl_xor(l0[r], off, 64);
            float mn = fmaxf(m0[r], m2);
            l0[r] = l0[r] * __expf(m0[r] - mn) + l2 * __expf(m2 - mn);
            m0[r] = mn;
        }
    }
    if (n16 == 0) {
        #pragma unroll
        for (int r = 0; r < 4; ++r) {
            const size_t idx = (size_t)(hL + rbase + quad * 4 + r) * 4 + j4;
            rowM4[idx] = m0[r];
            rowL4[idx] = l0[r];
        }
    }
}

// ---------------------------------------------------------------------------
// K3: P + PV over one j-half (16 chunks). Merges the 4 stats partials.
// P stored NT scalar from acc (no fp32 LDS stage); bf16 P staged in
// wave-private LDS for PV A-frags; Vt frags loaded from global (L2-hit).
// O partial (f32) per j-half -> k_ored reduce.
// b: [2:0]=xcd, [7:3]=tile, [8]=jh, [9]=hbit; h=(b&7)*2+(b>>9).
// ---------------------------------------------------------------------------
__global__ __launch_bounds__(256, 4) void k_pv(
    const unsigned short* __restrict__ Chi, const unsigned short* __restrict__ Clo,
    const unsigned short* __restrict__ TileB, const unsigned short* __restrict__ Vt,
    const float* __restrict__ rowM4, const float* __restrict__ rowL4,
    float* __restrict__ oPart, float* __restrict__ outP)
{
    __shared__ unsigned short sB[2][TILE_B];    // 2 x 8KB B tiles
    __shared__ unsigned short Ps[4][16 * 68];   // bf16 P, per wave
    const int b = blockIdx.x;
    const int h = (b & 7) * 2 + (b >> 9);
    const int tile = (b >> 3) & 31;
    const int jh = (b >> 8) & 1;
    const int tid = threadIdx.x, w = tid >> 6, lane = tid & 63;
    const int quad = lane >> 4, n16 = lane & 15;
    const int rbase = tile * 64 + w * 16;
    const int hL = h * LN;
    unsigned short* ps = &Ps[w][0];

    const bf16x8 ahi = *reinterpret_cast<const bf16x8*>(Chi + (size_t)(hL + rbase + n16) * KR + quad * 8);
    const bf16x8 alo = *reinterpret_cast<const bf16x8*>(Clo + (size_t)(hL + rbase + n16) * KR + quad * 8);

    const char* tBase = (const char*)(TileB + (size_t)(h * 32) * TILE_B);
    const int fragB = (quad * 64 + n16) * 8;
    const int srcOff = w * 2048 + lane * 16;
    const int jc0 = jh * 16;

    const unsigned short* vrow[4];
    #pragma unroll
    for (int di = 0; di < 4; ++di)
        vrow[di] = Vt + (size_t)(h * 64 + di * 16 + n16) * LN + quad * 8;

    // merge the 4 stats partials (same for both jh blocks)
    float mr[4], li[4];
    #pragma unroll
    for (int r = 0; r < 4; ++r) {
        const size_t idx = (size_t)(hL + rbase + quad * 4 + r) * 4;
        float ma = rowM4[idx], mb = rowM4[idx+1], mc = rowM4[idx+2], md = rowM4[idx+3];
        float la = rowL4[idx], lb = rowL4[idx+1], lc = rowL4[idx+2], ld = rowL4[idx+3];
        float m = fmaxf(fmaxf(ma, mb), fmaxf(mc, md));
        float l = la * __expf(ma - m) + lb * __expf(mb - m)
                + lc * __expf(mc - m) + ld * __expf(md - m);
        mr[r] = m;
        li[r] = 1.f / l;
    }

    f32x4 zero = {0.f, 0.f, 0.f, 0.f};
    f32x4 o[4];
    #pragma unroll
    for (int di = 0; di < 4; ++di) o[di] = zero;

    {   // prologue: chunk jc0 -> buf 0
        const char* g = tBase + (size_t)jc0 * 8192;
        char* d = (char*)sB[0];
        glds16(g + srcOff, d + w * 2048);
        glds16(g + srcOff + 1024, d + w * 2048 + 1024);
    }
    for (int ji = 0; ji < 16; ++ji) {
        __syncthreads();                         // drain DMA(cur) + prev compute
        const int cur = ji & 1;
        if (ji + 1 < 16) {
            const char* g = tBase + (size_t)(jc0 + ji + 1) * 8192;
            char* d = (char*)sB[cur ^ 1];
            glds16(g + srcOff, d + w * 2048);
            glds16(g + srcOff + 1024, d + w * 2048 + 1024);
        }
        const unsigned short* t = sB[cur];
        const int jb = (jc0 + ji) * 64;
        #pragma unroll
        for (int ni = 0; ni < 4; ++ni) {
            bf16x8 bhi = *reinterpret_cast<const bf16x8*>(t + fragB + ni * 128);
            bf16x8 blo = *reinterpret_cast<const bf16x8*>(t + 2048 + fragB + ni * 128);
            f32x4 acc = zero;
            acc = __builtin_amdgcn_mfma_f32_16x16x32_bf16(ahi, bhi, acc, 0, 0, 0);
            acc = __builtin_amdgcn_mfma_f32_16x16x32_bf16(ahi, blo, acc, 0, 0, 0);
            acc = __builtin_amdgcn_mfma_f32_16x16x32_bf16(alo, bhi, acc, 0, 0, 0);
            acc = __builtin_amdgcn_mfma_f32_16x16x32_bf16(alo, blo, acc, 0, 0, 0);
            #pragma unroll
            for (int r = 0; r < 4; ++r) {
                float p = __expf(acc[r] - mr[r]) * li[r];
                __builtin_nontemporal_store(p,
                    outP + (size_t)(hL + rbase + quad * 4 + r) * LN + jb + ni * 16 + n16);
                ps[(quad * 4 + r) * 68 + ni * 16 + n16] = f2b(p);
            }
        }
        // PV: O += P(chunk) @ V(chunk); Vt frags from global (L2-resident);
        // in-wave LDS RAW on ps ordered by compiler lgkmcnt.
        #pragma unroll
        for (int ks = 0; ks < 2; ++ks) {
            const bf16x8 pa = *reinterpret_cast<const bf16x8*>(ps + n16 * 68 + ks * 32 + quad * 8);
            #pragma unroll
            for (int di = 0; di < 4; ++di) {
                const bf16x8 vb = *reinterpret_cast<const bf16x8*>(vrow[di] + jb + ks * 32);
                o[di] = __builtin_amdgcn_mfma_f32_16x16x32_bf16(pa, vb, o[di], 0, 0, 0);
            }
        }
    }
    float* op = oPart + (size_t)jh * HN * LN * 64;
    #pragma unroll
    for (int di = 0; di < 4; ++di) {
        #pragma unroll
        for (int r = 0; r < 4; ++r) {
            const int grow = rbase + quad * 4 + r;
            op[(size_t)(hL + grow) * 64 + di * 16 + n16] = o[di][r];
        }
    }
}

// ---------------------------------------------------------------------------
// K4: O = oPart0 + oPart1  (2M floats)
// ---------------------------------------------------------------------------
__global__ __launch_bounds__(256) void k_ored(
    const float* __restrict__ oPart, float* __restrict__ outO)
{
    const int i = blockIdx.x * 256 + threadIdx.x;
    const f32x4* p0 = reinterpret_cast<const f32x4*>(oPart);
    const f32x4* p1 = reinterpret_cast<const f32x4*>(oPart + (size_t)HN * LN * 64);
    f32x4 a = p0[i], b = p1[i];
    f32x4 s = {a[0] + b[0], a[1] + b[1], a[2] + b[2], a[3] + b[3]};
    __builtin_nontemporal_store(s, reinterpret_cast<f32x4*>(outO) + i);
}

// ---------------------------------------------------------------------------
extern "C" void kernel_launch(void* const* d_in, const int* in_sizes, int n_in,
                              void* d_out, int out_size, void* d_ws, size_t ws_size,
                              hipStream_t stream)
{
    (void)in_sizes; (void)n_in; (void)out_size; (void)ws_size;
    const float* q  = (const float*)d_in[0];
    const float* v  = (const float*)d_in[1];
    const float* Wa = (const float*)d_in[2];
    const float* ba = (const float*)d_in[3];
    const float* Wb = (const float*)d_in[4];
    const float* bb = (const float*)d_in[5];

    float* out = (float*)d_out;
    char* wsb = (char*)d_ws;
    const size_t MB = 1024 * 1024;
    unsigned short* Chi   = (unsigned short*)(wsb);            // 2MB
    unsigned short* Clo   = (unsigned short*)(wsb + 2 * MB);   // 2MB
    unsigned short* TileB = (unsigned short*)(wsb + 4 * MB);   // 4MB (512 x 8KB)
    unsigned short* Vt    = (unsigned short*)(wsb + 8 * MB);   // 4MB
    float* rowM4 = (float*)(wsb + 12 * MB);                    // 512KB
    float* rowL4 = (float*)(wsb + 12 * MB + 512 * 1024);       // 512KB
    float* oPart = (float*)(wsb + 13 * MB);                    // 16MB

    float* outO = out;                          // [H*L*64]
    float* outP = out + (size_t)HN * LN * 64;   // [H*L*L]

    hipLaunchKernelGGL(k_cb, dim3(512), dim3(256), 0, stream,
                       q, Wa, ba, Wb, bb, Chi, Clo, TileB);
    hipLaunchKernelGGL(k_vt, dim3(512), dim3(256), 0, stream, v, Vt);
    hipLaunchKernelGGL(k_stats, dim3(2048), dim3(256), 0, stream,
                       Chi, Clo, TileB, rowM4, rowL4);
    hipLaunchKernelGGL(k_pv, dim3(1024), dim3(256), 0, stream,
                       Chi, Clo, TileB, Vt, rowM4, rowL4, oPart, outP);
    hipLaunchKernelGGL(k_ored, dim3(2048), dim3(256), 0, stream, oPart, outO);
}

// Round 11
// 412.048 us; speedup vs baseline: 1.0215x; 1.0215x over previous
//
#include <hip/hip_runtime.h>
#include <hip/hip_bf16.h>

// FactorizedDenseAttention, MI355X/gfx950.  ALL I/O FP32.
// S[i,j] = sum_m C[i,m]*B[j,m], C = 32*(a[2m]+a[2m+1]) (rank 32)
//   a = q@Wa^T+ba (64ch), B = q@Wb^T+bb (32ch); P = softmax(S); O = P@v.
// d_out = [O: H*L*64 f32][P: H*L*L f32].
// R11: R9's single-S fused kernel + THE FIX: O epilogue multiplies by li
// (R9/R10 accumulated o = sum p_hat*V with ps holding UNNORMALIZED p_hat
// but never applied 1/l -> absmax 2.73 on O, bit-identical across two sync
// regimes = deterministic logic bug, not a race). Dbuf prefetch restored
// (R9 choreography is WAR-safe: prefetch issued post-barrier). ps stride 72.

#define HN 16
#define LN 2048
#define KR 32

typedef __attribute__((ext_vector_type(8))) short bf16x8;
typedef __attribute__((ext_vector_type(4))) float f32x4;

__device__ __forceinline__ float b2f(unsigned short u) {
    return __uint_as_float(((unsigned int)u) << 16);
}
__device__ __forceinline__ unsigned short f2b(float f) {
    __hip_bfloat16 h = __float2bfloat16(f);   // RNE
    return *reinterpret_cast<unsigned short*>(&h);
}
__device__ __forceinline__ void glds16(const void* g, void* l) {
    // src: per-lane global addr; dst: wave-uniform LDS base (HW adds lane*16)
    __builtin_amdgcn_global_load_lds(
        (const __attribute__((address_space(1))) unsigned int*)g,
        (__attribute__((address_space(3))) unsigned int*)l, 16, 0, 0);
}

// B-tile per (h, jc): 8KB = 4096 shorts:
//   [0,2048): Bhi [kg=0..3][c=0..63] granules of 8 bf16 (k=kg*8..+8)
//   [2048,4096): Blo same
// V-tile per (h, jc): 8KB = 4096 shorts: [jg=0..7][d=0..63] granules of 8
//   bf16 = bf16(v[h][jc*64+jg*8 .. +8][d])
#define TILE_B 4096
#define TILE_V 4096

// ---------------------------------------------------------------------------
// K1a: thread = (row, kg): 8 m's. Weights in LDS. Chi/Clo row-major (A-frag
// layout), Bhi/Blo in 8KB tile-granule layout.  [validated R8]
// ---------------------------------------------------------------------------
__global__ __launch_bounds__(256) void k_cb(
    const float* __restrict__ q,
    const float* __restrict__ Wa, const float* __restrict__ ba,
    const float* __restrict__ Wb, const float* __restrict__ bb,
    unsigned short* __restrict__ Chi, unsigned short* __restrict__ Clo,
    unsigned short* __restrict__ TileB)
{
    __shared__ float sWa[64 * 64];
    __shared__ float sWb[32 * 64];
    __shared__ float sba[64];
    __shared__ float sbb[32];
    const int tid = threadIdx.x;
    for (int i = tid; i < 64 * 64; i += 256) sWa[i] = Wa[i];
    for (int i = tid; i < 32 * 64; i += 256) sWb[i] = Wb[i];
    if (tid < 64) sba[tid] = ba[tid];
    if (tid < 32) sbb[tid] = bb[tid];
    __syncthreads();

    const int t = blockIdx.x * 256 + tid;
    const int row = t >> 2, kg = t & 3, mh = kg * 8;   // m in [mh, mh+8)
    const int h = row >> 11, i = row & 2047;
    const int jc = i >> 6, c = i & 63;

    float qf[64];
    const float4* q4p = reinterpret_cast<const float4*>(q + (size_t)row * 64);
    #pragma unroll
    for (int k4 = 0; k4 < 16; ++k4) {
        float4 u = q4p[k4];
        qf[4*k4+0] = u.x; qf[4*k4+1] = u.y; qf[4*k4+2] = u.z; qf[4*k4+3] = u.w;
    }
    unsigned short chb[8], clb[8], bhb[8], blb[8];
    #pragma unroll
    for (int mi = 0; mi < 8; ++mi) {
        const int m = mh + mi;
        float a0 = sba[2*m], a1 = sba[2*m+1], bv = sbb[m];
        const float4* wa0 = reinterpret_cast<const float4*>(&sWa[(2*m) * 64]);
        const float4* wa1 = reinterpret_cast<const float4*>(&sWa[(2*m+1) * 64]);
        const float4* wb0 = reinterpret_cast<const float4*>(&sWb[m * 64]);
        #pragma unroll
        for (int k4 = 0; k4 < 16; ++k4) {
            float4 w0 = wa0[k4], w1 = wa1[k4], w2 = wb0[k4];
            float x0 = qf[4*k4], x1 = qf[4*k4+1], x2 = qf[4*k4+2], x3 = qf[4*k4+3];
            a0 = fmaf(x0, w0.x, a0); a0 = fmaf(x1, w0.y, a0);
            a0 = fmaf(x2, w0.z, a0); a0 = fmaf(x3, w0.w, a0);
            a1 = fmaf(x0, w1.x, a1); a1 = fmaf(x1, w1.y, a1);
            a1 = fmaf(x2, w1.z, a1); a1 = fmaf(x3, w1.w, a1);
            bv = fmaf(x0, w2.x, bv); bv = fmaf(x1, w2.y, bv);
            bv = fmaf(x2, w2.z, bv); bv = fmaf(x3, w2.w, bv);
        }
        float cc = 32.f * (a0 + a1);                  // fold repeat factor
        unsigned short ch = f2b(cc);
        chb[mi] = ch; clb[mi] = f2b(cc - b2f(ch));
        unsigned short bh = f2b(bv);
        bhb[mi] = bh; blb[mi] = f2b(bv - b2f(bh));
    }
    *reinterpret_cast<uint4*>(Chi + (size_t)row * KR + mh) = *reinterpret_cast<uint4*>(chb);
    *reinterpret_cast<uint4*>(Clo + (size_t)row * KR + mh) = *reinterpret_cast<uint4*>(clb);
    unsigned short* tb = TileB + (size_t)(h * 32 + jc) * TILE_B + (kg * 64 + c) * 8;
    *reinterpret_cast<uint4*>(tb)        = *reinterpret_cast<uint4*>(bhb);
    *reinterpret_cast<uint4*>(tb + 2048) = *reinterpret_cast<uint4*>(blb);
}

// ---------------------------------------------------------------------------
// K1b: V tiles (granule layout) via LDS transpose.  [validated R6/R7]
// ---------------------------------------------------------------------------
__global__ __launch_bounds__(256) void k_vtc(
    const float* __restrict__ v, unsigned short* __restrict__ TileV)
{
    __shared__ unsigned short sv[64 * 66];   // [j][d], stride 66
    const int tid = threadIdx.x;
    const int h = blockIdx.x >> 5, jc = blockIdx.x & 31;
    const float* src = v + (size_t)(h * LN + jc * 64) * 64;
    for (int i = tid; i < 4096; i += 256)
        sv[(i >> 6) * 66 + (i & 63)] = f2b(src[i]);
    __syncthreads();
    unsigned short* vt = TileV + (size_t)(h * 32 + jc) * TILE_V;
    #pragma unroll
    for (int it = 0; it < 2; ++it) {
        const int gi = tid + it * 256;               // 0..511
        const int jg = gi >> 6, d = gi & 63;
        unsigned short g8[8];
        #pragma unroll
        for (int jj = 0; jj < 8; ++jj)
            g8[jj] = sv[(jg * 8 + jj) * 66 + d];
        *reinterpret_cast<uint4*>(vt + (jg * 64 + d) * 8) = *reinterpret_cast<uint4*>(g8);
    }
}

// ---------------------------------------------------------------------------
// K2 (fused, single-S, dbuf): 16-row blocks, 2048 total. Wave w owns
// col-subtile w in loop1 and d-slice w in loop2; S strip in 128 VGPRs.
// Prefetch is issued post-barrier into the idle buffer (WAR-safe: all waves
// finished reading it before any wave passes the barrier).
// b: [2:0]=xcd, [9:3]=tile(128), [10]=hbit; h=(b&7)*2+(b>>10).
// ---------------------------------------------------------------------------
__global__ __launch_bounds__(256, 2) void k_fuse(
    const unsigned short* __restrict__ Chi, const unsigned short* __restrict__ Clo,
    const unsigned short* __restrict__ TileB, const unsigned short* __restrict__ TileV,
    float* __restrict__ outO, float* __restrict__ outP)
{
    __shared__ unsigned short sB[2][TILE_B];     // B dbuf, 2 x 8KB
    __shared__ unsigned short sV[2][TILE_V];     // V dbuf, 2 x 8KB
    __shared__ unsigned short ps[2][16 * 72];    // bf16 p_hat dbuf, stride 72
    __shared__ float sRedM[4][16];
    __shared__ float sRedL[4][16];

    const int b = blockIdx.x;
    const int h = (b & 7) * 2 + (b >> 10);       // XCD-aware head mapping
    const int tile = (b >> 3) & 127;
    const int tid = threadIdx.x, w = tid >> 6, lane = tid & 63;
    const int quad = lane >> 4, n16 = lane & 15;
    const int rbase = tile * 16;
    const int hL = h * LN;

    const bf16x8 ahi = *reinterpret_cast<const bf16x8*>(Chi + (size_t)(hL + rbase + n16) * KR + quad * 8);
    const bf16x8 alo = *reinterpret_cast<const bf16x8*>(Clo + (size_t)(hL + rbase + n16) * KR + quad * 8);

    const char* bBase = (const char*)(TileB + (size_t)(h * 32) * TILE_B);
    const char* vBase = (const char*)(TileV + (size_t)(h * 32) * TILE_V);
    const int srcOff = w * 2048 + lane * 16;     // wave w stages bytes [w*2K, +2K)
    const int fragW = (quad * 64 + w * 16 + n16) * 8;

    f32x4 zero = {0.f, 0.f, 0.f, 0.f};
    f32x4 sS[32];                                 // the S strip (128 VGPRs)

    // ---- loop 1: S -> registers (B dbuf + prefetch) ----
    {
        char* d = (char*)sB[0];
        glds16(bBase + srcOff,        d + w * 2048);
        glds16(bBase + srcOff + 1024, d + w * 2048 + 1024);
    }
    #pragma unroll
    for (int jc = 0; jc < 32; ++jc) {
        const int cur = jc & 1;
        __syncthreads();                          // drain DMA(cur), all waves
        if (jc + 1 < 32) {                        // prefetch next -> idle buf
            const char* g = bBase + (size_t)(jc + 1) * (TILE_B * 2);
            char* d = (char*)sB[cur ^ 1];
            glds16(g + srcOff,        d + w * 2048);
            glds16(g + srcOff + 1024, d + w * 2048 + 1024);
        }
        const unsigned short* t = sB[cur];
        bf16x8 bhi = *reinterpret_cast<const bf16x8*>(t + fragW);
        bf16x8 blo = *reinterpret_cast<const bf16x8*>(t + 2048 + fragW);
        f32x4 acc = zero;
        acc = __builtin_amdgcn_mfma_f32_16x16x32_bf16(ahi, bhi, acc, 0, 0, 0);
        acc = __builtin_amdgcn_mfma_f32_16x16x32_bf16(ahi, blo, acc, 0, 0, 0);
        acc = __builtin_amdgcn_mfma_f32_16x16x32_bf16(alo, bhi, acc, 0, 0, 0);
        sS[jc] = acc;
    }

    // ---- stats in registers: m, then S -> p_hat with l accumulation ----
    float mr[4], li[4];
    {
        float m0[4];
        #pragma unroll
        for (int r = 0; r < 4; ++r) {
            float mm = sS[0][r];
            #pragma unroll
            for (int jc = 1; jc < 32; ++jc) mm = fmaxf(mm, sS[jc][r]);
            #pragma unroll
            for (int off = 1; off <= 8; off <<= 1)
                mm = fmaxf(mm, __shfl_xor(mm, off, 64));
            m0[r] = mm;
        }
        __syncthreads();                          // loop1 sB reads done
        if (n16 == 0) {
            #pragma unroll
            for (int r = 0; r < 4; ++r) sRedM[w][quad * 4 + r] = m0[r];
        }
        __syncthreads();
        #pragma unroll
        for (int r = 0; r < 4; ++r)
            mr[r] = fmaxf(fmaxf(sRedM[0][quad*4+r], sRedM[1][quad*4+r]),
                          fmaxf(sRedM[2][quad*4+r], sRedM[3][quad*4+r]));
        float l0[4] = {0.f, 0.f, 0.f, 0.f};
        #pragma unroll
        for (int jc = 0; jc < 32; ++jc) {
            #pragma unroll
            for (int r = 0; r < 4; ++r) {
                float p = __expf(sS[jc][r] - mr[r]);  // <= 1, = 1 at the max
                sS[jc][r] = p;
                l0[r] += p;
            }
        }
        #pragma unroll
        for (int r = 0; r < 4; ++r) {
            float ll = l0[r];
            #pragma unroll
            for (int off = 1; off <= 8; off <<= 1)
                ll += __shfl_xor(ll, off, 64);
            l0[r] = ll;
        }
        if (n16 == 0) {
            #pragma unroll
            for (int r = 0; r < 4; ++r) sRedL[w][quad * 4 + r] = l0[r];
        }
        __syncthreads();
        #pragma unroll
        for (int r = 0; r < 4; ++r)
            li[r] = 1.f / (sRedL[0][quad*4+r] + sRedL[1][quad*4+r]
                         + sRedL[2][quad*4+r] + sRedL[3][quad*4+r]);
    }

    // ---- loop 2: P writes + PV (V dbuf + ps dbuf + prefetch) ----
    f32x4 o = zero;
    {   // prologues: V chunk 0 -> sV[0], p_hat chunk 0 -> ps[0]
        char* d = (char*)sV[0];
        glds16(vBase + srcOff,        d + w * 2048);
        glds16(vBase + srcOff + 1024, d + w * 2048 + 1024);
        #pragma unroll
        for (int r = 0; r < 4; ++r)
            ps[0][(quad * 4 + r) * 72 + w * 16 + n16] = f2b(sS[0][r]);
    }
    #pragma unroll
    for (int jc = 0; jc < 32; ++jc) {
        const int cur = jc & 1;
        __syncthreads();                // V DMA(cur) drained, ps[cur] visible
        if (jc + 1 < 32) {              // prefetch next V + next p_hat
            const char* g = vBase + (size_t)(jc + 1) * (TILE_V * 2);
            char* d = (char*)sV[cur ^ 1];
            glds16(g + srcOff,        d + w * 2048);
            glds16(g + srcOff + 1024, d + w * 2048 + 1024);
            #pragma unroll
            for (int r = 0; r < 4; ++r)
                ps[cur ^ 1][(quad * 4 + r) * 72 + w * 16 + n16] = f2b(sS[jc + 1][r]);
        }
        const int jb = jc * 64;
        #pragma unroll
        for (int r = 0; r < 4; ++r)
            __builtin_nontemporal_store(sS[jc][r] * li[r],
                outP + (size_t)(hL + rbase + quad * 4 + r) * LN + jb + w * 16 + n16);
        #pragma unroll
        for (int ks = 0; ks < 2; ++ks) {
            bf16x8 pa = *reinterpret_cast<const bf16x8*>(&ps[cur][n16 * 72 + ks * 32 + quad * 8]);
            bf16x8 vb = *reinterpret_cast<const bf16x8*>(
                sV[cur] + ((ks * 4 + quad) * 64 + w * 16 + n16) * 8);
            o = __builtin_amdgcn_mfma_f32_16x16x32_bf16(pa, vb, o, 0, 0, 0);
        }
    }
    // O = (sum p_hat * V) * li   <-- THE R9/R10 BUG: li was missing here
    #pragma unroll
    for (int r = 0; r < 4; ++r)
        __builtin_nontemporal_store(o[r] * li[r],
            &outO[(size_t)(hL + rbase + quad * 4 + r) * 64 + w * 16 + n16]);
}

// ---------------------------------------------------------------------------
extern "C" void kernel_launch(void* const* d_in, const int* in_sizes, int n_in,
                              void* d_out, int out_size, void* d_ws, size_t ws_size,
                              hipStream_t stream)
{
    (void)in_sizes; (void)n_in; (void)out_size; (void)ws_size;
    const float* q  = (const float*)d_in[0];
    const float* v  = (const float*)d_in[1];
    const float* Wa = (const float*)d_in[2];
    const float* ba = (const float*)d_in[3];
    const float* Wb = (const float*)d_in[4];
    const float* bb = (const float*)d_in[5];

    float* out = (float*)d_out;
    char* wsb = (char*)d_ws;
    const size_t MB = 1024 * 1024;
    unsigned short* Chi   = (unsigned short*)(wsb);            // 2MB
    unsigned short* Clo   = (unsigned short*)(wsb + 2 * MB);   // 2MB
    unsigned short* TileB = (unsigned short*)(wsb + 4 * MB);   // 4MB (512 x 8KB)
    unsigned short* TileV = (unsigned short*)(wsb + 8 * MB);   // 4MB (512 x 8KB)

    float* outO = out;                          // [H*L*64]
    float* outP = out + (size_t)HN * LN * 64;   // [H*L*L]

    hipLaunchKernelGGL(k_cb, dim3(512), dim3(256), 0, stream,
                       q, Wa, ba, Wb, bb, Chi, Clo, TileB);
    hipLaunchKernelGGL(k_vtc, dim3(512), dim3(256), 0, stream, v, TileV);
    hipLaunchKernelGGL(k_fuse, dim3(2048), dim3(256), 0, stream,
                       Chi, Clo, TileB, TileV, outO, outP);
}

// Round 12
// 384.265 us; speedup vs baseline: 1.0954x; 1.0723x over previous
//
#include <hip/hip_runtime.h>
#include <hip/hip_bf16.h>

// FactorizedDenseAttention, MI355X/gfx950.  ALL I/O FP32.
// S[i,j] = sum_m C[i,m]*B[j,m], C = 32*(a[2m]+a[2m+1]) (rank 32)
//   a = q@Wa^T+ba (64ch), B = q@Wb^T+bb (32ch); P = softmax(S); O = P@v.
// d_out = [O: H*L*64 f32][P: H*L*L f32].
// R12: barrier elimination. R11 (412us) lost to R7 (389) because 16-row
// blocks left ~15cyc of compute between 64 DMA-draining barriers.
//   loop1: B-frags read DIRECTLY from global (16B/lane, granule layout,
//          L2-resident) -> no LDS, no DMA, no barriers, compiler pipelines
//          32 independent chunks;
//   loop2: V-frags direct from global; p_hat cross-wave exchange via a
//          half-width LDS buffer (16x1024 bf16), filled twice -> 3 barriers;
//   stats: 2 barriers. Total 5 barriers/block (was 64+).
// Math identical to R11 (3-MFMA S, single exp, O*li fix kept).

#define HN 16
#define LN 2048
#define KR 32

typedef __attribute__((ext_vector_type(8))) short bf16x8;
typedef __attribute__((ext_vector_type(4))) float f32x4;

__device__ __forceinline__ float b2f(unsigned short u) {
    return __uint_as_float(((unsigned int)u) << 16);
}
__device__ __forceinline__ unsigned short f2b(float f) {
    __hip_bfloat16 h = __float2bfloat16(f);   // RNE
    return *reinterpret_cast<unsigned short*>(&h);
}

// B-tile per (h, jc): 8KB = 4096 shorts:
//   [0,2048): Bhi [kg=0..3][c=0..63] granules of 8 bf16 (k=kg*8..+8)
//   [2048,4096): Blo same
// V-tile per (h, jc): 8KB = 4096 shorts: [jg=0..7][d=0..63] granules of 8
//   bf16 = bf16(v[h][jc*64+jg*8 .. +8][d])
#define TILE_B 4096
#define TILE_V 4096

// ---------------------------------------------------------------------------
// K1a: thread = (row, kg): 8 m's. Weights in LDS. Chi/Clo row-major (A-frag
// layout), Bhi/Blo in 8KB tile-granule layout.  [validated R8-R11]
// ---------------------------------------------------------------------------
__global__ __launch_bounds__(256) void k_cb(
    const float* __restrict__ q,
    const float* __restrict__ Wa, const float* __restrict__ ba,
    const float* __restrict__ Wb, const float* __restrict__ bb,
    unsigned short* __restrict__ Chi, unsigned short* __restrict__ Clo,
    unsigned short* __restrict__ TileB)
{
    __shared__ float sWa[64 * 64];
    __shared__ float sWb[32 * 64];
    __shared__ float sba[64];
    __shared__ float sbb[32];
    const int tid = threadIdx.x;
    for (int i = tid; i < 64 * 64; i += 256) sWa[i] = Wa[i];
    for (int i = tid; i < 32 * 64; i += 256) sWb[i] = Wb[i];
    if (tid < 64) sba[tid] = ba[tid];
    if (tid < 32) sbb[tid] = bb[tid];
    __syncthreads();

    const int t = blockIdx.x * 256 + tid;
    const int row = t >> 2, kg = t & 3, mh = kg * 8;   // m in [mh, mh+8)
    const int h = row >> 11, i = row & 2047;
    const int jc = i >> 6, c = i & 63;

    float qf[64];
    const float4* q4p = reinterpret_cast<const float4*>(q + (size_t)row * 64);
    #pragma unroll
    for (int k4 = 0; k4 < 16; ++k4) {
        float4 u = q4p[k4];
        qf[4*k4+0] = u.x; qf[4*k4+1] = u.y; qf[4*k4+2] = u.z; qf[4*k4+3] = u.w;
    }
    unsigned short chb[8], clb[8], bhb[8], blb[8];
    #pragma unroll
    for (int mi = 0; mi < 8; ++mi) {
        const int m = mh + mi;
        float a0 = sba[2*m], a1 = sba[2*m+1], bv = sbb[m];
        const float4* wa0 = reinterpret_cast<const float4*>(&sWa[(2*m) * 64]);
        const float4* wa1 = reinterpret_cast<const float4*>(&sWa[(2*m+1) * 64]);
        const float4* wb0 = reinterpret_cast<const float4*>(&sWb[m * 64]);
        #pragma unroll
        for (int k4 = 0; k4 < 16; ++k4) {
            float4 w0 = wa0[k4], w1 = wa1[k4], w2 = wb0[k4];
            float x0 = qf[4*k4], x1 = qf[4*k4+1], x2 = qf[4*k4+2], x3 = qf[4*k4+3];
            a0 = fmaf(x0, w0.x, a0); a0 = fmaf(x1, w0.y, a0);
            a0 = fmaf(x2, w0.z, a0); a0 = fmaf(x3, w0.w, a0);
            a1 = fmaf(x0, w1.x, a1); a1 = fmaf(x1, w1.y, a1);
            a1 = fmaf(x2, w1.z, a1); a1 = fmaf(x3, w1.w, a1);
            bv = fmaf(x0, w2.x, bv); bv = fmaf(x1, w2.y, bv);
            bv = fmaf(x2, w2.z, bv); bv = fmaf(x3, w2.w, bv);
        }
        float cc = 32.f * (a0 + a1);                  // fold repeat factor
        unsigned short ch = f2b(cc);
        chb[mi] = ch; clb[mi] = f2b(cc - b2f(ch));
        unsigned short bh = f2b(bv);
        bhb[mi] = bh; blb[mi] = f2b(bv - b2f(bh));
    }
    *reinterpret_cast<uint4*>(Chi + (size_t)row * KR + mh) = *reinterpret_cast<uint4*>(chb);
    *reinterpret_cast<uint4*>(Clo + (size_t)row * KR + mh) = *reinterpret_cast<uint4*>(clb);
    unsigned short* tb = TileB + (size_t)(h * 32 + jc) * TILE_B + (kg * 64 + c) * 8;
    *reinterpret_cast<uint4*>(tb)        = *reinterpret_cast<uint4*>(bhb);
    *reinterpret_cast<uint4*>(tb + 2048) = *reinterpret_cast<uint4*>(blb);
}

// ---------------------------------------------------------------------------
// K1b: V tiles (granule layout) via LDS transpose.  [validated R6-R11]
// ---------------------------------------------------------------------------
__global__ __launch_bounds__(256) void k_vtc(
    const float* __restrict__ v, unsigned short* __restrict__ TileV)
{
    __shared__ unsigned short sv[64 * 66];   // [j][d], stride 66
    const int tid = threadIdx.x;
    const int h = blockIdx.x >> 5, jc = blockIdx.x & 31;
    const float* src = v + (size_t)(h * LN + jc * 64) * 64;
    for (int i = tid; i < 4096; i += 256)
        sv[(i >> 6) * 66 + (i & 63)] = f2b(src[i]);
    __syncthreads();
    unsigned short* vt = TileV + (size_t)(h * 32 + jc) * TILE_V;
    #pragma unroll
    for (int it = 0; it < 2; ++it) {
        const int gi = tid + it * 256;               // 0..511
        const int jg = gi >> 6, d = gi & 63;
        unsigned short g8[8];
        #pragma unroll
        for (int jj = 0; jj < 8; ++jj)
            g8[jj] = sv[(jg * 8 + jj) * 66 + d];
        *reinterpret_cast<uint4*>(vt + (jg * 64 + d) * 8) = *reinterpret_cast<uint4*>(g8);
    }
}

// ---------------------------------------------------------------------------
// K2 (fused, single-S, near-barrier-free): 16-row blocks, 2048 total.
// Wave w owns col-subtile w (loop1) and d-slice w (loop2); S in 128 VGPRs.
// B/V fragments read directly from global (L2-resident granule tiles).
// p_hat exchanged via half-width LDS (16 x 1024 bf16), filled per 16 chunks.
// b: [2:0]=xcd, [9:3]=tile(128), [10]=hbit; h=(b&7)*2+(b>>10).
// ---------------------------------------------------------------------------
#define PS_STRIDE 1032
__global__ __launch_bounds__(256, 2) void k_fuse(
    const unsigned short* __restrict__ Chi, const unsigned short* __restrict__ Clo,
    const unsigned short* __restrict__ TileB, const unsigned short* __restrict__ TileV,
    float* __restrict__ outO, float* __restrict__ outP)
{
    __shared__ unsigned short ps[16 * PS_STRIDE];   // 33KB: 16 rows x 1024 cols
    __shared__ float sRedM[4][16];
    __shared__ float sRedL[4][16];

    const int b = blockIdx.x;
    const int h = (b & 7) * 2 + (b >> 10);       // XCD-aware head mapping
    const int tile = (b >> 3) & 127;
    const int tid = threadIdx.x, w = tid >> 6, lane = tid & 63;
    const int quad = lane >> 4, n16 = lane & 15;
    const int rbase = tile * 16;
    const int hL = h * LN;

    const bf16x8 ahi = *reinterpret_cast<const bf16x8*>(Chi + (size_t)(hL + rbase + n16) * KR + quad * 8);
    const bf16x8 alo = *reinterpret_cast<const bf16x8*>(Clo + (size_t)(hL + rbase + n16) * KR + quad * 8);

    const unsigned short* bTile = TileB + (size_t)(h * 32) * TILE_B;
    const unsigned short* vTile = TileV + (size_t)(h * 32) * TILE_V;
    const int fragW = (quad * 64 + w * 16 + n16) * 8;   // B granule, shorts

    f32x4 zero = {0.f, 0.f, 0.f, 0.f};
    f32x4 sS[32];                                 // the S strip (128 VGPRs)

    // ---- loop 1: S -> registers, B-frags direct from global (no barriers) ----
    #pragma unroll
    for (int jc = 0; jc < 32; ++jc) {
        const unsigned short* g = bTile + jc * TILE_B;
        bf16x8 bhi = *reinterpret_cast<const bf16x8*>(g + fragW);
        bf16x8 blo = *reinterpret_cast<const bf16x8*>(g + 2048 + fragW);
        f32x4 acc = zero;
        acc = __builtin_amdgcn_mfma_f32_16x16x32_bf16(ahi, bhi, acc, 0, 0, 0);
        acc = __builtin_amdgcn_mfma_f32_16x16x32_bf16(ahi, blo, acc, 0, 0, 0);
        acc = __builtin_amdgcn_mfma_f32_16x16x32_bf16(alo, bhi, acc, 0, 0, 0);
        sS[jc] = acc;
    }

    // ---- stats in registers: m, then S -> p_hat with l accumulation ----
    float mr[4], li[4];
    {
        float m0[4];
        #pragma unroll
        for (int r = 0; r < 4; ++r) {
            float mm = sS[0][r];
            #pragma unroll
            for (int jc = 1; jc < 32; ++jc) mm = fmaxf(mm, sS[jc][r]);
            #pragma unroll
            for (int off = 1; off <= 8; off <<= 1)
                mm = fmaxf(mm, __shfl_xor(mm, off, 64));
            m0[r] = mm;
        }
        if (n16 == 0) {
            #pragma unroll
            for (int r = 0; r < 4; ++r) sRedM[w][quad * 4 + r] = m0[r];
        }
        __syncthreads();
        #pragma unroll
        for (int r = 0; r < 4; ++r)
            mr[r] = fmaxf(fmaxf(sRedM[0][quad*4+r], sRedM[1][quad*4+r]),
                          fmaxf(sRedM[2][quad*4+r], sRedM[3][quad*4+r]));
        float l0[4] = {0.f, 0.f, 0.f, 0.f};
        #pragma unroll
        for (int jc = 0; jc < 32; ++jc) {
            #pragma unroll
            for (int r = 0; r < 4; ++r) {
                float p = __expf(sS[jc][r] - mr[r]);  // <= 1, = 1 at the max
                sS[jc][r] = p;
                l0[r] += p;
            }
        }
        #pragma unroll
        for (int r = 0; r < 4; ++r) {
            float ll = l0[r];
            #pragma unroll
            for (int off = 1; off <= 8; off <<= 1)
                ll += __shfl_xor(ll, off, 64);
            l0[r] = ll;
        }
        if (n16 == 0) {
            #pragma unroll
            for (int r = 0; r < 4; ++r) sRedL[w][quad * 4 + r] = l0[r];
        }
        __syncthreads();
        #pragma unroll
        for (int r = 0; r < 4; ++r)
            li[r] = 1.f / (sRedL[0][quad*4+r] + sRedL[1][quad*4+r]
                         + sRedL[2][quad*4+r] + sRedL[3][quad*4+r]);
    }

    // ---- loop 2: two 16-chunk halves; per half: fill ps, barrier, then
    //      barrier-free PV with V-frags direct from global ----
    f32x4 o = zero;
    #pragma unroll
    for (int half = 0; half < 2; ++half) {
        if (half) __syncthreads();           // PV(half 0) ps reads complete
        const int jc0 = half * 16;
        #pragma unroll
        for (int ji = 0; ji < 16; ++ji) {
            #pragma unroll
            for (int r = 0; r < 4; ++r)
                ps[(quad * 4 + r) * PS_STRIDE + ji * 64 + w * 16 + n16]
                    = f2b(sS[jc0 + ji][r]);
        }
        __syncthreads();                     // ps visible to all waves
        #pragma unroll
        for (int ji = 0; ji < 16; ++ji) {
            const int jc = jc0 + ji;
            const int jb = jc * 64;
            #pragma unroll
            for (int r = 0; r < 4; ++r)
                __builtin_nontemporal_store(sS[jc][r] * li[r],
                    outP + (size_t)(hL + rbase + quad * 4 + r) * LN + jb + w * 16 + n16);
            const unsigned short* vt = vTile + jc * TILE_V;
            #pragma unroll
            for (int ks = 0; ks < 2; ++ks) {
                bf16x8 pa = *reinterpret_cast<const bf16x8*>(
                    ps + n16 * PS_STRIDE + ji * 64 + ks * 32 + quad * 8);
                bf16x8 vb = *reinterpret_cast<const bf16x8*>(
                    vt + ((ks * 4 + quad) * 64 + w * 16 + n16) * 8);
                o = __builtin_amdgcn_mfma_f32_16x16x32_bf16(pa, vb, o, 0, 0, 0);
            }
        }
    }
    // O = (sum p_hat * V) * li
    #pragma unroll
    for (int r = 0; r < 4; ++r)
        __builtin_nontemporal_store(o[r] * li[r],
            &outO[(size_t)(hL + rbase + quad * 4 + r) * 64 + w * 16 + n16]);
}

// ---------------------------------------------------------------------------
extern "C" void kernel_launch(void* const* d_in, const int* in_sizes, int n_in,
                              void* d_out, int out_size, void* d_ws, size_t ws_size,
                              hipStream_t stream)
{
    (void)in_sizes; (void)n_in; (void)out_size; (void)ws_size;
    const float* q  = (const float*)d_in[0];
    const float* v  = (const float*)d_in[1];
    const float* Wa = (const float*)d_in[2];
    const float* ba = (const float*)d_in[3];
    const float* Wb = (const float*)d_in[4];
    const float* bb = (const float*)d_in[5];

    float* out = (float*)d_out;
    char* wsb = (char*)d_ws;
    const size_t MB = 1024 * 1024;
    unsigned short* Chi   = (unsigned short*)(wsb);            // 2MB
    unsigned short* Clo   = (unsigned short*)(wsb + 2 * MB);   // 2MB
    unsigned short* TileB = (unsigned short*)(wsb + 4 * MB);   // 4MB (512 x 8KB)
    unsigned short* TileV = (unsigned short*)(wsb + 8 * MB);   // 4MB (512 x 8KB)

    float* outO = out;                          // [H*L*64]
    float* outP = out + (size_t)HN * LN * 64;   // [H*L*L]

    hipLaunchKernelGGL(k_cb, dim3(512), dim3(256), 0, stream,
                       q, Wa, ba, Wb, bb, Chi, Clo, TileB);
    hipLaunchKernelGGL(k_vtc, dim3(512), dim3(256), 0, stream, v, TileV);
    hipLaunchKernelGGL(k_fuse, dim3(2048), dim3(256), 0, stream,
                       Chi, Clo, TileB, TileV, outO, outP);
}